// Round 6
// baseline (6036.566 us; speedup 1.0000x reference)
//
#include <hip/hip_runtime.h>
#include <cstdint>
#include <cmath>

// Problem constants
constexpr int SEQ  = 2048;   // sequence length S
constexpr int EMB  = 512;    // embed dim E
constexpr int HID  = 256;    // per-direction hidden H
constexpr int GATE = 1024;   // 4*H
constexpr int NTAG = 32;     // tagset T
constexpr float FNEG = -10000.0f;
constexpr int NBLK = 128;    // launched LSTM blocks (workers self-select)
constexpr int NWORK = 16;    // 8 blocks per direction actually work

// ---------------------------------------------------------------------------
// Kernel 1: px[dir][s][j] = emb[t_eff(dir,s)] . w_ih_dir[j] + b_dir[j]
// ---------------------------------------------------------------------------
__global__ __launch_bounds__(256) void px_gemm(
    const int* __restrict__ sent, const float* __restrict__ embed,
    const float* __restrict__ w_ih_f, const float* __restrict__ b_f,
    const float* __restrict__ w_ih_b, const float* __restrict__ b_b,
    float* __restrict__ px)
{
  const int dir = blockIdx.z;
  const int tm = blockIdx.x, tn = blockIdx.y;
  const float* __restrict__ w_ih = dir ? w_ih_b : w_ih_f;
  const float* __restrict__ bias = dir ? b_b : b_f;
  __shared__ float As[64][65];   // +1 pad -> 2-way max bank aliasing (free)
  __shared__ float Bs[64][65];
  __shared__ int sidx[64];
  const int tid = threadIdx.x;
  if (tid < 64) {
    const int s = tm * 64 + tid;
    const int tpos = dir ? (SEQ - 1 - s) : s;
    sidx[tid] = sent[tpos];
  }
  __syncthreads();
  float acc[4][4] = {};
  const int tr = tid >> 4, tc = tid & 15;
  for (int k0 = 0; k0 < EMB; k0 += 64) {
    #pragma unroll
    for (int i = 0; i < 4; ++i) {
      const int v = tid + i * 256;           // 1024 float4 slots: 64 rows x 16
      const int r = v >> 4, kv = v & 15;
      const float4 a4 = *reinterpret_cast<const float4*>(
          &embed[(size_t)sidx[r] * EMB + k0 + kv * 4]);
      As[r][kv*4+0] = a4.x; As[r][kv*4+1] = a4.y;
      As[r][kv*4+2] = a4.z; As[r][kv*4+3] = a4.w;
      const float4 b4 = *reinterpret_cast<const float4*>(
          &w_ih[(size_t)(tn * 64 + r) * EMB + k0 + kv * 4]);
      Bs[r][kv*4+0] = b4.x; Bs[r][kv*4+1] = b4.y;
      Bs[r][kv*4+2] = b4.z; Bs[r][kv*4+3] = b4.w;
    }
    __syncthreads();
    #pragma unroll
    for (int kk = 0; kk < 64; ++kk) {
      float a[4], b[4];
      #pragma unroll
      for (int i = 0; i < 4; ++i) a[i] = As[tr + 16 * i][kk];
      #pragma unroll
      for (int jj = 0; jj < 4; ++jj) b[jj] = Bs[tc + 16 * jj][kk];
      #pragma unroll
      for (int i = 0; i < 4; ++i)
        #pragma unroll
        for (int jj = 0; jj < 4; ++jj)
          acc[i][jj] = fmaf(a[i], b[jj], acc[i][jj]);
    }
    __syncthreads();
  }
  #pragma unroll
  for (int i = 0; i < 4; ++i) {
    const int srow = tm * 64 + tr + 16 * i;
    #pragma unroll
    for (int jj = 0; jj < 4; ++jj) {
      const int j = tn * 64 + tc + 16 * jj;   // tc fastest -> coalesced stores
      px[((size_t)dir * SEQ + srow) * GATE + j] = acc[i][jj] + bias[j];
    }
  }
}

// ---------------------------------------------------------------------------
// ctl[0]=reg_count ctl[1..8]=xcd_count ctl[9]=chosen(0x100|xcd) ctl[10]=claim
// ---------------------------------------------------------------------------
__global__ void init_ctl(unsigned* ctl) {
  if (threadIdx.x < 16) ctl[threadIdx.x] = 0u;
}

// sc0+sc1 load: bypass L1 and L2, read LLC (device-correct fallback).
__device__ __forceinline__ unsigned long long ld_llc(
    const unsigned long long* p) {
  unsigned long long v;
  asm volatile("global_load_dwordx2 %0, %1, off sc0 sc1\n\ts_waitcnt vmcnt(0)"
               : "=v"(v) : "v"(p) : "memory");
  return v;
}
// Dual sc0 load (L1-bypass, L2-served): poll the plain-store packet (p2,
// fast visibility via write-through L1 -> local L2) AND the agent-store
// packet (p1, R5's proven path) under one vmcnt(0).
__device__ __forceinline__ void ld_dual(
    const unsigned long long* p2, const unsigned long long* p1,
    unsigned long long& v2, unsigned long long& v1) {
  asm volatile("global_load_dwordx2 %0, %2, off sc0\n\t"
               "global_load_dwordx2 %1, %3, off sc0\n\t"
               "s_waitcnt vmcnt(0)"
               : "=&v"(v2), "=&v"(v1) : "v"(p2), "v"(p1) : "memory");
}

// ---------------------------------------------------------------------------
// Kernel 2: LSTM recurrence. R5 post-mortem: polls are L2-served (FETCH
// 46->18 MB as predicted) yet time barely moved -> the dominant sync term is
// PUBLISH-TO-VISIBLE latency of the agent-scope (sc0 sc1) store, which must
// trek to the LLC before readers tag-match. Fix: dual publish. A plain
// global store writes through the (write-through) vector L1 into the local
// XCD L2 in ~150-200 cyc; same-XCD sc0 readers are served by that L2. The
// agent-scope store is kept as the proven correctness path; each poll round
// issues both loads and takes whichever tags first (worst case == R5).
// Per-lane sticky demote to LLC polling after 400 rounds keeps Guideline-16
// safety. No sleep for the first 32 rounds (R5's sleep-after-4 quantized
// detection into 364-cyc ticks).
// Compute layout unchanged since R2 (absmax 0.0): thread (j=tid>>3, q=tid&7)
// owns unit u=32b+j, K-slice [32q,32q+32) in 32 float4 regs (unified-RF
// resident; rocprof VGPR_Count=132 excludes AGPRs); shfl-reduce over 8
// lanes; c in lane q==0; h double-buffered in LDS; one barrier per step.
// ---------------------------------------------------------------------------
__global__ __attribute__((amdgpu_flat_work_group_size(256, 256),
                          amdgpu_waves_per_eu(1, 1)))
void lstm_xcd(
    const float* __restrict__ px, const float* __restrict__ w_hh_f,
    const float* __restrict__ w_hh_b, const float* __restrict__ h0,
    const float* __restrict__ c0, float* __restrict__ hs,
    unsigned long long* __restrict__ hx,
    unsigned long long* __restrict__ hx2, unsigned* __restrict__ ctl)
{
  const int tid = threadIdx.x;
  __shared__ int s_asn;
  if (tid == 0) {
    // HW_REG_XCC_ID: id=20, offset=0, size=32 -> imm 63508 [m09]
    unsigned xcd = __builtin_amdgcn_s_getreg(63508) & 7u;
    atomicAdd(&ctl[1 + xcd], 1u);
    __threadfence();
    atomicAdd(&ctl[0], 1u);
    if (blockIdx.x == 0) {
      while (__hip_atomic_load(&ctl[0], __ATOMIC_RELAXED,
                               __HIP_MEMORY_SCOPE_AGENT) < (unsigned)NBLK)
        __builtin_amdgcn_s_sleep(16);
      __threadfence();
      unsigned best = 0, bc = 0;
      for (unsigned x = 0; x < 8; ++x) {
        const unsigned cx = __hip_atomic_load(&ctl[1 + x], __ATOMIC_RELAXED,
                                              __HIP_MEMORY_SCOPE_AGENT);
        if (cx > bc) { bc = cx; best = x; }
      }
      __hip_atomic_store(&ctl[9], 0x100u | best, __ATOMIC_RELAXED,
                         __HIP_MEMORY_SCOPE_AGENT);
    }
    unsigned ch;
    while (((ch = __hip_atomic_load(&ctl[9], __ATOMIC_RELAXED,
                                    __HIP_MEMORY_SCOPE_AGENT)) & 0x100u) == 0)
      __builtin_amdgcn_s_sleep(16);
    int mine = -1;
    if ((ch & 7u) == xcd) {
      const unsigned idx = atomicAdd(&ctl[10], 1u);
      if (idx < (unsigned)NWORK) mine = (int)idx;
    }
    s_asn = mine;
  }
  __syncthreads();
  const int asn = s_asn;
  if (asn < 0) return;                      // non-worker: uniform exit
  const int dir = asn >> 3, b = asn & 7;

  const int j = tid >> 3;          // unit within block's 32
  const int q = tid & 7;           // K-slice index (32 floats each)
  const int u = 32 * b + j;        // global hidden unit
  const float* __restrict__ w_hh = dir ? w_hh_b : w_hh_f;

  // Weight fragments: rows u, 256+u, 512+u, 768+u; cols [32q, 32q+32)
  float4 wi[8], wf[8], wg[8], wo[8];
  {
    const float* __restrict__ r0 = &w_hh[(size_t)u * HID + 32 * q];
    const float* __restrict__ r1 = r0 + (size_t)256 * HID;
    const float* __restrict__ r2 = r0 + (size_t)512 * HID;
    const float* __restrict__ r3 = r0 + (size_t)768 * HID;
    #pragma unroll
    for (int m = 0; m < 8; ++m) {
      wi[m] = *reinterpret_cast<const float4*>(&r0[4 * m]);
      wf[m] = *reinterpret_cast<const float4*>(&r1[4 * m]);
      wg[m] = *reinterpret_cast<const float4*>(&r2[4 * m]);
      wo[m] = *reinterpret_cast<const float4*>(&r3[4 * m]);
    }
  }

  // h double-buffered; chunk g at 36g (bank-spread pad, conflict-free b128)
  __shared__ float hsh[2][8 * 36];
  float c = 0.0f;
  hsh[0][36 * (tid >> 5) + (tid & 31)] = h0[dir * HID + tid];
  if (q == 0) c = c0[dir * HID + u];
  __syncthreads();

  const size_t pxbase = (size_t)dir * SEQ * GATE;
  float pi = 0.f, pf = 0.f, pg = 0.f, po = 0.f;
  if (q == 0) {
    pi = px[pxbase + u];        pf = px[pxbase + 256 + u];
    pg = px[pxbase + 512 + u];  po = px[pxbase + 768 + u];
  }

  bool fast = true;   // sticky: demoted to LLC polling if L2 path stalls
  for (int t = 0; t < SEQ; ++t) {
    const float* __restrict__ hb = hsh[t & 1];
    float*       __restrict__ nb = hsh[(t & 1) ^ 1];

    // prefetch next step's px behind the FMA phase
    float ni = 0.f, nf = 0.f, ng = 0.f, no = 0.f;
    if (q == 0 && t + 1 < SEQ) {
      const size_t nbx = pxbase + (size_t)(t + 1) * GATE;
      ni = px[nbx + u];        nf = px[nbx + 256 + u];
      ng = px[nbx + 512 + u];  no = px[nbx + 768 + u];
    }

    float si = 0.f, sf = 0.f, sg = 0.f, so = 0.f;
    #pragma unroll
    for (int m = 0; m < 8; ++m) {
      const float4 h4 = *reinterpret_cast<const float4*>(&hb[36 * q + 4 * m]);
      si = fmaf(h4.x, wi[m].x, si); si = fmaf(h4.y, wi[m].y, si);
      si = fmaf(h4.z, wi[m].z, si); si = fmaf(h4.w, wi[m].w, si);
      sf = fmaf(h4.x, wf[m].x, sf); sf = fmaf(h4.y, wf[m].y, sf);
      sf = fmaf(h4.z, wf[m].z, sf); sf = fmaf(h4.w, wf[m].w, sf);
      sg = fmaf(h4.x, wg[m].x, sg); sg = fmaf(h4.y, wg[m].y, sg);
      sg = fmaf(h4.z, wg[m].z, sg); sg = fmaf(h4.w, wg[m].w, sg);
      so = fmaf(h4.x, wo[m].x, so); so = fmaf(h4.y, wo[m].y, so);
      so = fmaf(h4.z, wo[m].z, so); so = fmaf(h4.w, wo[m].w, so);
    }
    #pragma unroll
    for (int off = 4; off >= 1; off >>= 1) {
      si += __shfl_down(si, off, 8);
      sf += __shfl_down(sf, off, 8);
      sg += __shfl_down(sg, off, 8);
      so += __shfl_down(so, off, 8);
    }

    if (q == 0) {
      const float gi = si + pi, gf = sf + pf, gg = sg + pg, go = so + po;
      const float ai = 1.0f / (1.0f + expf(-gi));
      const float af = 1.0f / (1.0f + expf(-gf));
      const float ao = 1.0f / (1.0f + expf(-go));
      c = af * c + ai * tanhf(gg);
      const float hn = ao * tanhf(c);
      const unsigned long long pk =
          ((unsigned long long)(unsigned)(t + 1) << 32) |
          (unsigned long long)__float_as_uint(hn);
      const size_t pidx = ((size_t)dir * SEQ + t) * HID + u;
      hx2[pidx] = pk;   // plain store: write-through L1 -> local L2 (fast)
      __hip_atomic_store(&hx[pidx], pk, __ATOMIC_RELAXED,
                         __HIP_MEMORY_SCOPE_AGENT);   // LLC (proven path)
      nb[36 * b + j] = hn;           // own chunk: LDS direct
      hs[pidx] = hn;
    }
    pi = ni; pf = nf; pg = ng; po = no;
    if (t == SEQ - 1) break;     // uniform: no one consumes the last broadcast

    // gather the other 224 units' tagged packets
    {
      const size_t gidx = ((size_t)dir * SEQ + t) * HID + tid;
      const unsigned long long* p1 = &hx[gidx];
      const unsigned long long* p2 = &hx2[gidx];
      const unsigned want = (unsigned)(t + 1);
      bool need = (tid >> 5) != b;   // own 32 units arrived via LDS
      int rounds = 0;
      while (true) {
        if (need) {
          unsigned long long v = 0;
          if (fast) {
            unsigned long long v2, v1;
            ld_dual(p2, p1, v2, v1);
            if ((unsigned)(v2 >> 32) == want) v = v2;
            else if ((unsigned)(v1 >> 32) == want) v = v1;
          } else {
            const unsigned long long v1 = ld_llc(p1);
            if ((unsigned)(v1 >> 32) == want) v = v1;
          }
          if ((unsigned)(v >> 32) == want) {
            nb[36 * (tid >> 5) + (tid & 31)] = __uint_as_float((unsigned)v);
            need = false;
          }
        }
        if (__ballot(need) == 0ULL) break;
        ++rounds;
        if (rounds > 400) fast = false;   // misplaced: demote to LLC polling
        if (rounds > 32) __builtin_amdgcn_s_sleep(1);
      }
    }
    __syncthreads();   // nb fully populated; hb no longer needed
  }
}

// ---------------------------------------------------------------------------
// Kernel 3: feats[t][j] = concat(h_fwd[t], h_bwd[S-1-t]) . w_tag[j] + b_tag[j]
// ---------------------------------------------------------------------------
__global__ __launch_bounds__(256) void feats_kernel(
    const float* __restrict__ hs, const float* __restrict__ w_tag,
    const float* __restrict__ b_tag, float* __restrict__ feats)
{
  const int t = blockIdx.x;
  const int tid = threadIdx.x;
  const int j = tid >> 3, p = tid & 7;
  const float* __restrict__ src = (p < 4)
      ? (hs + (size_t)t * HID + p * 64)                              // fwd half
      : (hs + (size_t)(SEQ + (SEQ - 1 - t)) * HID + (p - 4) * 64);   // bwd half
  const float* __restrict__ wt = w_tag + (size_t)j * (2 * HID) + p * 64;
  float sum = 0.f;
  #pragma unroll
  for (int k = 0; k < 64; k += 4) {
    const float4 x4 = *reinterpret_cast<const float4*>(&src[k]);
    const float4 w4 = *reinterpret_cast<const float4*>(&wt[k]);
    sum = fmaf(x4.x, w4.x, sum); sum = fmaf(x4.y, w4.y, sum);
    sum = fmaf(x4.z, w4.z, sum); sum = fmaf(x4.w, w4.w, sum);
  }
  sum += __shfl_down(sum, 4, 8);
  sum += __shfl_down(sum, 2, 8);
  sum += __shfl_down(sum, 1, 8);
  if (p == 0) feats[(size_t)t * NTAG + j] = sum + b_tag[j];
}

// ---------------------------------------------------------------------------
// Kernel 4: Viterbi + backtrace, single wave. Tie-breaking matches
// jnp.argmax (first index): strict '>' updates, lower half wins ties.
// ---------------------------------------------------------------------------
__global__ __launch_bounds__(64) void viterbi_kernel(
    const float* __restrict__ feats, const float* __restrict__ trans,
    float* __restrict__ out)
{
  __shared__ unsigned char bp[SEQ][NTAG];   // 64 KiB exactly
  const int lane = threadIdx.x;
  const int j = lane & 31, half = lane >> 5;
  float tr[16];
  #pragma unroll
  for (int qq = 0; qq < 16; ++qq) tr[qq] = trans[j * NTAG + half * 16 + qq];
  float fv = (j == 30) ? 0.0f : FNEG;       // START = 30
  float fcur = feats[j];
  for (int t = 0; t < SEQ; ++t) {
    const int tn = (t + 1 < SEQ) ? (t + 1) : (SEQ - 1);
    const float fnext = feats[(size_t)tn * NTAG + j];
    float best = -3.0e38f; int barg = 0;
    #pragma unroll
    for (int qq = 0; qq < 16; ++qq) {
      const int p = half * 16 + qq;
      const float sc = __shfl(fv, p) + tr[qq];
      if (sc > best) { best = sc; barg = p; }
    }
    const float ob = __shfl_down(best, 32);
    const int   oa = __shfl_down(barg, 32);
    float fvnew = 0.f;
    if (half == 0) {
      if (ob > best) { best = ob; barg = oa; }
      bp[t][j] = (unsigned char)barg;
      fvnew = best + fcur;
    }
    fv = __shfl(fvnew, j);   // broadcast updated fv[j] to both halves
    fcur = fnext;
  }
  float term = fv + trans[31 * NTAG + j];   // STOP = 31
  int idx = j;
  #pragma unroll
  for (int off = 16; off >= 1; off >>= 1) {
    const float ov = __shfl_down(term, off, 32);
    const int   oi = __shfl_down(idx, off, 32);
    if (ov > term) { term = ov; idx = oi; }
  }
  if (lane == 0) {
    out[0] = term;                 // path score
    int tag = idx;
    for (int t = SEQ - 1; t >= 0; --t) {
      out[1 + t] = (float)tag;     // y[S-1] = best_last; y[t] = bp[t+1][y[t+1]]
      tag = bp[t][tag];
    }
  }
}

// ---------------------------------------------------------------------------
extern "C" void kernel_launch(void* const* d_in, const int* in_sizes, int n_in,
                              void* d_out, int out_size, void* d_ws, size_t ws_size,
                              hipStream_t stream)
{
  (void)in_sizes; (void)n_in; (void)out_size;
  const int*   sent   = (const int*)  d_in[0];
  const float* embed  = (const float*)d_in[1];
  const float* w_ih_f = (const float*)d_in[2];
  const float* w_hh_f = (const float*)d_in[3];
  const float* b_f    = (const float*)d_in[4];
  const float* w_ih_b = (const float*)d_in[5];
  const float* w_hh_b = (const float*)d_in[6];
  const float* b_b    = (const float*)d_in[7];
  const float* w_tag  = (const float*)d_in[8];
  const float* b_tag  = (const float*)d_in[9];
  const float* trans  = (const float*)d_in[10];
  const float* h0     = (const float*)d_in[11];
  const float* c0     = (const float*)d_in[12];
  float* out = (float*)d_out;

  // ws: hx[2][S][256] u64 | px[2][S][1024] f32 | hs[2][S][256] | feats | ctl
  //     | hx2[2][S][256] u64 (fast-visibility packets; aliases hx if ws is
  //       too small -> exact R5 behavior)
  unsigned long long* hx = (unsigned long long*)d_ws;          // 8 MB
  float* px    = (float*)(hx + (size_t)2 * SEQ * HID);         // 16 MB
  float* hsbuf = px + (size_t)2 * SEQ * GATE;                  // 4 MB
  float* feats = hsbuf + (size_t)2 * SEQ * HID;                // 256 KB
  unsigned* ctl = (unsigned*)(feats + (size_t)SEQ * NTAG);     // 64 B
  unsigned long long* hx2 = (unsigned long long*)(ctl + 16);
  const size_t need = (size_t)((char*)(hx2 + (size_t)2 * SEQ * HID) -
                               (char*)d_ws);
  if (ws_size < need) hx2 = hx;   // graceful degrade: dual paths coincide

  init_ctl<<<1, 64, 0, stream>>>(ctl);
  dim3 gemm_grid(SEQ / 64, GATE / 64, 2);
  px_gemm<<<gemm_grid, 256, 0, stream>>>(sent, embed, w_ih_f, b_f,
                                         w_ih_b, b_b, px);
  lstm_xcd<<<NBLK, 256, 0, stream>>>(px, w_hh_f, w_hh_b, h0, c0,
                                     hsbuf, hx, hx2, ctl);
  feats_kernel<<<SEQ, 256, 0, stream>>>(hsbuf, w_tag, b_tag, feats);
  viterbi_kernel<<<1, 64, 0, stream>>>(feats, trans, out);
}